// Round 3
// baseline (431.103 us; speedup 1.0000x reference)
//
#include <hip/hip_runtime.h>
#include <hip/hip_fp16.h>

// 3-layer gather-GEMM GNN (N=262144, K=8, 16->128->128->16), f16 MFMA.
// Round 3: no-LDS design. Each lane loads its MFMA A-fragment (16 B slice of
// one neighbor row) directly from global — same HBM traffic as LDS staging
// (4 quads x 16 B = one 64 B line per row per k-step), but no barriers, no
// bank conflicts, no LDS occupancy cap; waves free-run and hide gather
// latency with their own unrolled loads.
// Scaled messages prescaled by 2^-8 (folded into inv_dist) to avoid fp16
// overflow; epilogue multiplies accumulator by 256 before bias.
//
// Workspace: ws holds ONLY h1+h2 (128 MiB exactly). invd/h16/shuffled-W live
// in d_out (scratch until layer 2 overwrites it); layer 2's invd+Wf2 are
// d2d-copied into the dead h1 region first.

typedef _Float16 f16x8 __attribute__((ext_vector_type(8)));
typedef float f32x4 __attribute__((ext_vector_type(4)));

#define NNODES 262144

__global__ __launch_bounds__(256) void conv_h_kernel(const float* __restrict__ h,
                                                     __half* __restrict__ h16, int n) {
    int i = blockIdx.x * 256 + threadIdx.x;
    if (i < n) h16[i] = __float2half(h[i]);
}

__global__ __launch_bounds__(256) void prep_edges_kernel(const float* __restrict__ pos,
                                                         const int* __restrict__ nbr,
                                                         __half* __restrict__ invd, int n_edges) {
    int e = blockIdx.x * 256 + threadIdx.x;
    if (e >= n_edges) return;
    int i = e >> 3;
    int n = nbr[e];
    float dx = pos[i * 3 + 0] - pos[n * 3 + 0];
    float dy = pos[i * 3 + 1] - pos[n * 3 + 1];
    float dz = pos[i * 3 + 2] - pos[n * 3 + 2];
    float d = sqrtf(dx * dx + dy * dy + dz * dz);
    if (d == 0.0f) d = 0.5f;                       // reference: where(dist==0, 0.5, dist)
    invd[e] = __float2half((1.0f / d) * 0.00390625f);  // prescale 1/256
}

// Pre-shuffle W [KT][FO] (row-major f32) into MFMA B-fragment order:
// Wf[((s*NT + t)*64 + lane)*8 + j] = W[s*32 + (lane>>4)*8 + j][t*16 + (lane&15)]
__global__ __launch_bounds__(256) void shuffle_w_kernel(const float* __restrict__ W,
                                                        __half* __restrict__ Wf,
                                                        int KT, int FO) {
    int e = blockIdx.x * 256 + threadIdx.x;
    if (e >= KT * FO) return;
    int j = e & 7;
    int lane = (e >> 3) & 63;
    int rest = e >> 9;
    int NT = FO >> 4;
    int t = rest % NT;
    int s = rest / NT;
    int k = s * 32 + (lane >> 4) * 8 + j;
    int n = t * 16 + (lane & 15);
    Wf[e] = __float2half(W[k * FO + n]);
}

// Fused gather + scale + GEMM layer, direct-register A-fragments (no LDS).
template <int F_IN, int F_OUT, bool LEAKY, bool OUT_F32>
__global__ __launch_bounds__(256) void layer_kernel(
    const __half* __restrict__ hprev, const __half* __restrict__ invd,
    const int* __restrict__ nbr, const __half* __restrict__ Wf,
    const float* __restrict__ bias, void* __restrict__ outp) {
    constexpr int NT = F_OUT / 16;

    const int tid = threadIdx.x;
    const int wave = tid >> 6;
    const int lane = tid & 63;
    const int quad = lane >> 4;
    const int lmod = lane & 15;

    // This lane's A row (same row for all 4 quads; quad selects k-slice).
    const int m = blockIdx.x * 64 + wave * 16 + lmod;

    // Per-row neighbor indices + prescaled inverse distances.
    const int4* nrow = (const int4*)(nbr + (size_t)m * 8);
    const int4 idxA = nrow[0];
    const int4 idxB = nrow[1];
    const int idx[8] = {idxA.x, idxA.y, idxA.z, idxA.w, idxB.x, idxB.y, idxB.z, idxB.w};
    const f16x8 invrow = *(const f16x8*)(invd + (size_t)m * 8);

    f32x4 acc[NT];
#pragma unroll
    for (int t = 0; t < NT; ++t) acc[t] = f32x4{0.f, 0.f, 0.f, 0.f};

    if (F_IN == 128) {
#pragma unroll
        for (int nb = 0; nb < 8; ++nb) {
            const size_t base = (size_t)idx[nb] * 128;
            const _Float16 sc = invrow[nb];
            f16x8 a[4];
#pragma unroll
            for (int ks = 0; ks < 4; ++ks)
                a[ks] = *(const f16x8*)(hprev + base + ks * 32 + quad * 8);
#pragma unroll
            for (int ks = 0; ks < 4; ++ks) a[ks] = a[ks] * sc;
#pragma unroll
            for (int ks = 0; ks < 4; ++ks) {
                const int s = nb * 4 + ks;
#pragma unroll
                for (int t = 0; t < NT; ++t) {
                    f16x8 b = *(const f16x8*)(Wf + (size_t)(((s * NT) + t) * 64 + lane) * 8);
                    acc[t] = __builtin_amdgcn_mfma_f32_16x16x32_f16(a[ks], b, acc[t], 0, 0, 0);
                }
            }
        }
    } else {
        // F_IN == 16: K=128, 4 k-steps; k = s*32 + quad*8 + j -> neighbor
        // nb = 2s + (quad>>1), feature f = (quad&1)*8 + j.
#pragma unroll
        for (int s = 0; s < 4; ++s) {
            const int nb = 2 * s + (quad >> 1);
            const size_t base = (size_t)idx[nb] * 16 + (quad & 1) * 8;
            f16x8 a = *(const f16x8*)(hprev + base);
            a = a * invrow[nb];
#pragma unroll
            for (int t = 0; t < NT; ++t) {
                f16x8 b = *(const f16x8*)(Wf + (size_t)(((s * NT) + t) * 64 + lane) * 8);
                acc[t] = __builtin_amdgcn_mfma_f32_16x16x32_f16(a, b, acc[t], 0, 0, 0);
            }
        }
    }

    // Epilogue: D[row=quad*4+rr][col=lane&15] per 16x16 tile.
    const int rbase = blockIdx.x * 64 + wave * 16 + quad * 4;
#pragma unroll
    for (int t = 0; t < NT; ++t) {
        const int col = t * 16 + lmod;
        const float bv = bias[col];
#pragma unroll
        for (int rr = 0; rr < 4; ++rr) {
            const int grow = rbase + rr;
            float v = acc[t][rr] * 256.0f + bv;
            if (LEAKY) v = (v >= 0.f) ? v : 0.01f * v;
            if (OUT_F32)
                ((float*)outp)[(size_t)grow * F_OUT + col] = v;
            else
                ((__half*)outp)[(size_t)grow * F_OUT + col] = __float2half(v);
        }
    }
}

extern "C" void kernel_launch(void* const* d_in, const int* in_sizes, int n_in,
                              void* d_out, int out_size, void* d_ws, size_t ws_size,
                              hipStream_t stream) {
    const float* h   = (const float*)d_in[0];
    const float* pos = (const float*)d_in[1];
    const int*   nbr = (const int*)d_in[2];
    const float* W0  = (const float*)d_in[3];
    const float* b0  = (const float*)d_in[4];
    const float* W1  = (const float*)d_in[5];
    const float* b1  = (const float*)d_in[6];
    const float* W2  = (const float*)d_in[7];
    const float* b2  = (const float*)d_in[8];

    const int N = NNODES;

    // ws: ONLY the two 64 MiB fp16 intermediates (128 MiB total).
    char* w = (char*)d_ws;
    __half* h1 = (__half*)w;                               // 67,108,864 B
    __half* h2 = (__half*)(w + (size_t)67108864);          // 67,108,864 B
    // layer-2 copies of invd/Wf2, placed in the dead h1 region:
    __half* invd2 = (__half*)w;                            // 4,194,304 B
    __half* W2f2  = (__half*)(w + (size_t)4194304);        // 32,768 B

    // d_out doubles as scratch until layer 2 overwrites all of it (16 MiB).
    char* ob = (char*)d_out;
    __half* invd = (__half*)(ob + 0);                      // 4,194,304 B
    __half* h16  = (__half*)(ob + 4194304);                // 8,388,608 B
    __half* W0f  = (__half*)(ob + 12582912);               // 32,768 B
    __half* W1f  = (__half*)(ob + 12615680);               // 262,144 B
    __half* W2f  = (__half*)(ob + 12877824);               // 32,768 B  (end 12,910,592 <= 16,777,216)

    conv_h_kernel<<<(N * 16 + 255) / 256, 256, 0, stream>>>(h, h16, N * 16);
    prep_edges_kernel<<<(N * 8 + 255) / 256, 256, 0, stream>>>(pos, nbr, invd, N * 8);
    shuffle_w_kernel<<<(128 * 128 + 255) / 256, 256, 0, stream>>>(W0, W0f, 128, 128);
    shuffle_w_kernel<<<(1024 * 128 + 255) / 256, 256, 0, stream>>>(W1, W1f, 1024, 128);
    shuffle_w_kernel<<<(1024 * 16 + 255) / 256, 256, 0, stream>>>(W2, W2f, 1024, 16);

    layer_kernel<16, 128, false, false><<<N / 64, 256, 0, stream>>>(h16, invd, nbr, W0f, b0, h1);
    layer_kernel<128, 128, true, false><<<N / 64, 256, 0, stream>>>(h1, invd, nbr, W1f, b1, h2);

    // Move what layer 2 needs out of d_out (h1 is dead now).
    hipMemcpyAsync(invd2, invd, 4194304, hipMemcpyDeviceToDevice, stream);
    hipMemcpyAsync(W2f2, W2f, 32768, hipMemcpyDeviceToDevice, stream);

    layer_kernel<128, 16, false, true><<<N / 64, 256, 0, stream>>>(h2, invd2, nbr, W2f2, b2, d_out);
}

// Round 4
// 430.049 us; speedup vs baseline: 1.0025x; 1.0025x over previous
//
#include <hip/hip_runtime.h>
#include <hip/hip_fp16.h>

// 3-layer gather-GEMM GNN (N=262144, K=8, 16->128->128->16), f16 MFMA.
// Round 4: direct-register A gather + M_TILES=2 (32 rows/wave). Each B
// fragment load now feeds 2 MFMAs: halves Wf L1/L2 traffic and doubles
// compute per load-latency round (the round-3 bottleneck).
// Scaled messages prescaled by 2^-8 (folded into inv_dist); epilogue
// multiplies accumulator by 256 before bias.
//
// Workspace: ws holds ONLY h1+h2 (128 MiB exactly). invd/h16/shuffled-W live
// in d_out (scratch until layer 2 overwrites it); layer 2's invd+Wf2 are
// d2d-copied into the dead h1 region first.

typedef _Float16 f16x8 __attribute__((ext_vector_type(8)));
typedef float f32x4 __attribute__((ext_vector_type(4)));

#define NNODES 262144

__global__ __launch_bounds__(256) void conv_h_kernel(const float* __restrict__ h,
                                                     __half* __restrict__ h16, int n) {
    int i = blockIdx.x * 256 + threadIdx.x;
    if (i < n) h16[i] = __float2half(h[i]);
}

__global__ __launch_bounds__(256) void prep_edges_kernel(const float* __restrict__ pos,
                                                         const int* __restrict__ nbr,
                                                         __half* __restrict__ invd, int n_edges) {
    int e = blockIdx.x * 256 + threadIdx.x;
    if (e >= n_edges) return;
    int i = e >> 3;
    int n = nbr[e];
    float dx = pos[i * 3 + 0] - pos[n * 3 + 0];
    float dy = pos[i * 3 + 1] - pos[n * 3 + 1];
    float dz = pos[i * 3 + 2] - pos[n * 3 + 2];
    float d = sqrtf(dx * dx + dy * dy + dz * dz);
    if (d == 0.0f) d = 0.5f;                       // reference: where(dist==0, 0.5, dist)
    invd[e] = __float2half((1.0f / d) * 0.00390625f);  // prescale 1/256
}

// Pre-shuffle W [KT][FO] (row-major f32) into MFMA B-fragment order:
// Wf[((s*NT + t)*64 + lane)*8 + j] = W[s*32 + (lane>>4)*8 + j][t*16 + (lane&15)]
__global__ __launch_bounds__(256) void shuffle_w_kernel(const float* __restrict__ W,
                                                        __half* __restrict__ Wf,
                                                        int KT, int FO) {
    int e = blockIdx.x * 256 + threadIdx.x;
    if (e >= KT * FO) return;
    int j = e & 7;
    int lane = (e >> 3) & 63;
    int rest = e >> 9;
    int NT = FO >> 4;
    int t = rest % NT;
    int s = rest / NT;
    int k = s * 32 + (lane >> 4) * 8 + j;
    int n = t * 16 + (lane & 15);
    Wf[e] = __float2half(W[k * FO + n]);
}

// Fused gather + scale + GEMM layer, direct-register A-fragments, 2 M-tiles
// per wave (rows wave*16+lmod and +64 within a 128-row block).
template <int F_IN, int F_OUT, bool LEAKY, bool OUT_F32>
__global__ __launch_bounds__(256) void layer_kernel(
    const __half* __restrict__ hprev, const __half* __restrict__ invd,
    const int* __restrict__ nbr, const __half* __restrict__ Wf,
    const float* __restrict__ bias, void* __restrict__ outp) {
    constexpr int NT = F_OUT / 16;

    const int tid = threadIdx.x;
    const int wave = tid >> 6;
    const int lane = tid & 63;
    const int quad = lane >> 4;
    const int lmod = lane & 15;

    const int mbase = blockIdx.x * 128 + wave * 16 + lmod;

    int idx[2][8];
    f16x8 invr[2];
#pragma unroll
    for (int mt = 0; mt < 2; ++mt) {
        const int m = mbase + mt * 64;
        const int4* nrow = (const int4*)(nbr + (size_t)m * 8);
        const int4 iA = nrow[0];
        const int4 iB = nrow[1];
        idx[mt][0] = iA.x; idx[mt][1] = iA.y; idx[mt][2] = iA.z; idx[mt][3] = iA.w;
        idx[mt][4] = iB.x; idx[mt][5] = iB.y; idx[mt][6] = iB.z; idx[mt][7] = iB.w;
        invr[mt] = *(const f16x8*)(invd + (size_t)m * 8);
    }

    f32x4 acc[2][NT];
#pragma unroll
    for (int mt = 0; mt < 2; ++mt)
#pragma unroll
        for (int t = 0; t < NT; ++t) acc[mt][t] = f32x4{0.f, 0.f, 0.f, 0.f};

    if (F_IN == 128) {
#pragma unroll
        for (int nb = 0; nb < 8; ++nb) {
            f16x8 a[2][4];
#pragma unroll
            for (int mt = 0; mt < 2; ++mt) {
                const size_t base = (size_t)idx[mt][nb] * 128;
#pragma unroll
                for (int ks = 0; ks < 4; ++ks)
                    a[mt][ks] = *(const f16x8*)(hprev + base + ks * 32 + quad * 8);
            }
#pragma unroll
            for (int mt = 0; mt < 2; ++mt) {
                const _Float16 sc = invr[mt][nb];
#pragma unroll
                for (int ks = 0; ks < 4; ++ks) a[mt][ks] = a[mt][ks] * sc;
            }
#pragma unroll
            for (int ks = 0; ks < 4; ++ks) {
                const int s = nb * 4 + ks;
#pragma unroll
                for (int t = 0; t < NT; ++t) {
                    f16x8 b = *(const f16x8*)(Wf + (size_t)(((s * NT) + t) * 64 + lane) * 8);
                    acc[0][t] = __builtin_amdgcn_mfma_f32_16x16x32_f16(a[0][ks], b, acc[0][t], 0, 0, 0);
                    acc[1][t] = __builtin_amdgcn_mfma_f32_16x16x32_f16(a[1][ks], b, acc[1][t], 0, 0, 0);
                }
            }
        }
    } else {
        // F_IN == 16: K=128, 4 k-steps; k = s*32 + quad*8 + j -> neighbor
        // nb = 2s + (quad>>1), feature f = (quad&1)*8 + j.
#pragma unroll
        for (int s = 0; s < 4; ++s) {
            const int nb = 2 * s + (quad >> 1);
            f16x8 a[2];
#pragma unroll
            for (int mt = 0; mt < 2; ++mt) {
                a[mt] = *(const f16x8*)(hprev + (size_t)idx[mt][nb] * 16 + (quad & 1) * 8);
                a[mt] = a[mt] * invr[mt][nb];
            }
#pragma unroll
            for (int t = 0; t < NT; ++t) {
                f16x8 b = *(const f16x8*)(Wf + (size_t)(((s * NT) + t) * 64 + lane) * 8);
                acc[0][t] = __builtin_amdgcn_mfma_f32_16x16x32_f16(a[0], b, acc[0][t], 0, 0, 0);
                acc[1][t] = __builtin_amdgcn_mfma_f32_16x16x32_f16(a[1], b, acc[1][t], 0, 0, 0);
            }
        }
    }

    // Epilogue: D[row=quad*4+rr][col=lane&15] per 16x16 tile.
#pragma unroll
    for (int mt = 0; mt < 2; ++mt) {
        const int rbase = blockIdx.x * 128 + mt * 64 + wave * 16 + quad * 4;
#pragma unroll
        for (int t = 0; t < NT; ++t) {
            const int col = t * 16 + lmod;
            const float bv = bias[col];
#pragma unroll
            for (int rr = 0; rr < 4; ++rr) {
                const int grow = rbase + rr;
                float v = acc[mt][t][rr] * 256.0f + bv;
                if (LEAKY) v = (v >= 0.f) ? v : 0.01f * v;
                if (OUT_F32)
                    ((float*)outp)[(size_t)grow * F_OUT + col] = v;
                else
                    ((__half*)outp)[(size_t)grow * F_OUT + col] = __float2half(v);
            }
        }
    }
}

extern "C" void kernel_launch(void* const* d_in, const int* in_sizes, int n_in,
                              void* d_out, int out_size, void* d_ws, size_t ws_size,
                              hipStream_t stream) {
    const float* h   = (const float*)d_in[0];
    const float* pos = (const float*)d_in[1];
    const int*   nbr = (const int*)d_in[2];
    const float* W0  = (const float*)d_in[3];
    const float* b0  = (const float*)d_in[4];
    const float* W1  = (const float*)d_in[5];
    const float* b1  = (const float*)d_in[6];
    const float* W2  = (const float*)d_in[7];
    const float* b2  = (const float*)d_in[8];

    const int N = NNODES;

    // ws: ONLY the two 64 MiB fp16 intermediates (128 MiB total).
    char* w = (char*)d_ws;
    __half* h1 = (__half*)w;                               // 67,108,864 B
    __half* h2 = (__half*)(w + (size_t)67108864);          // 67,108,864 B
    // layer-2 copies of invd/Wf2, placed in the dead h1 region:
    __half* invd2 = (__half*)w;                            // 4,194,304 B
    __half* W2f2  = (__half*)(w + (size_t)4194304);        // 32,768 B

    // d_out doubles as scratch until layer 2 overwrites all of it (16 MiB).
    char* ob = (char*)d_out;
    __half* invd = (__half*)(ob + 0);                      // 4,194,304 B
    __half* h16  = (__half*)(ob + 4194304);                // 8,388,608 B
    __half* W0f  = (__half*)(ob + 12582912);               // 32,768 B
    __half* W1f  = (__half*)(ob + 12615680);               // 262,144 B
    __half* W2f  = (__half*)(ob + 12877824);               // 32,768 B  (end 12,910,592 <= 16,777,216)

    conv_h_kernel<<<(N * 16 + 255) / 256, 256, 0, stream>>>(h, h16, N * 16);
    prep_edges_kernel<<<(N * 8 + 255) / 256, 256, 0, stream>>>(pos, nbr, invd, N * 8);
    shuffle_w_kernel<<<(128 * 128 + 255) / 256, 256, 0, stream>>>(W0, W0f, 128, 128);
    shuffle_w_kernel<<<(1024 * 128 + 255) / 256, 256, 0, stream>>>(W1, W1f, 1024, 128);
    shuffle_w_kernel<<<(1024 * 16 + 255) / 256, 256, 0, stream>>>(W2, W2f, 1024, 16);

    layer_kernel<16, 128, false, false><<<N / 128, 256, 0, stream>>>(h16, invd, nbr, W0f, b0, h1);
    layer_kernel<128, 128, true, false><<<N / 128, 256, 0, stream>>>(h1, invd, nbr, W1f, b1, h2);

    // Move what layer 2 needs out of d_out (h1 is dead now).
    hipMemcpyAsync(invd2, invd, 4194304, hipMemcpyDeviceToDevice, stream);
    hipMemcpyAsync(W2f2, W2f, 32768, hipMemcpyDeviceToDevice, stream);

    layer_kernel<128, 16, false, true><<<N / 128, 256, 0, stream>>>(h2, invd2, nbr, W2f2, b2, d_out);
}

// Round 5
// 410.346 us; speedup vs baseline: 1.0506x; 1.0480x over previous
//
#include <hip/hip_runtime.h>
#include <hip/hip_fp16.h>

// 3-layer gather-GEMM GNN (N=262144, K=8, 16->128->128->16), f16 MFMA.
// Round 5: B fragments served from LDS (stage-once for the 32 KB weights of
// L0/L2; 2x16 KB double-buffered chunks for L1's 256 KB), A gathered directly
// to registers with next-neighbor prefetch. Removes the per-MFMA global
// B-load dependency (L2 ~200cyc) that capped MfmaUtil at ~14%.
// Scaled messages prescaled by 2^-8 (folded into inv_dist); epilogue
// multiplies accumulator by 256 before bias.
//
// Workspace: ws holds ONLY h1+h2 (128 MiB exactly). invd/h16/shuffled-W live
// in d_out (scratch until layer 2 overwrites it); layer 2's invd+Wf2 are
// d2d-copied into the dead h1 region first.

typedef _Float16 f16x8 __attribute__((ext_vector_type(8)));
typedef float f32x4 __attribute__((ext_vector_type(4)));

#define NNODES 262144

__global__ __launch_bounds__(256) void conv_h_kernel(const float* __restrict__ h,
                                                     __half* __restrict__ h16, int n) {
    int i = blockIdx.x * 256 + threadIdx.x;
    if (i < n) h16[i] = __float2half(h[i]);
}

__global__ __launch_bounds__(256) void prep_edges_kernel(const float* __restrict__ pos,
                                                         const int* __restrict__ nbr,
                                                         __half* __restrict__ invd, int n_edges) {
    int e = blockIdx.x * 256 + threadIdx.x;
    if (e >= n_edges) return;
    int i = e >> 3;
    int n = nbr[e];
    float dx = pos[i * 3 + 0] - pos[n * 3 + 0];
    float dy = pos[i * 3 + 1] - pos[n * 3 + 1];
    float dz = pos[i * 3 + 2] - pos[n * 3 + 2];
    float d = sqrtf(dx * dx + dy * dy + dz * dz);
    if (d == 0.0f) d = 0.5f;                       // reference: where(dist==0, 0.5, dist)
    invd[e] = __float2half((1.0f / d) * 0.00390625f);  // prescale 1/256
}

// Pre-shuffle W [KT][FO] (row-major f32) into MFMA B-fragment order:
// Wf[((s*NT + t)*64 + lane)*8 + j] = W[s*32 + (lane>>4)*8 + j][t*16 + (lane&15)]
__global__ __launch_bounds__(256) void shuffle_w_kernel(const float* __restrict__ W,
                                                        __half* __restrict__ Wf,
                                                        int KT, int FO) {
    int e = blockIdx.x * 256 + threadIdx.x;
    if (e >= KT * FO) return;
    int j = e & 7;
    int lane = (e >> 3) & 63;
    int rest = e >> 9;
    int NT = FO >> 4;
    int t = rest % NT;
    int s = rest / NT;
    int k = s * 32 + (lane >> 4) * 8 + j;
    int n = t * 16 + (lane & 15);
    Wf[e] = __float2half(W[k * FO + n]);
}

// Fused gather + scale + GEMM layer. B from LDS, A direct-gather w/ prefetch.
template <int F_IN, int F_OUT, int MT, bool LEAKY, bool OUT_F32>
__global__ __launch_bounds__(256) void layer_kernel(
    const __half* __restrict__ hprev, const __half* __restrict__ invd,
    const int* __restrict__ nbr, const __half* __restrict__ Wf,
    const float* __restrict__ bias, void* __restrict__ outp) {
    constexpr int NT = F_OUT / 16;
    constexpr bool CHUNKED = (F_IN == 128 && F_OUT == 128);  // Wf = 256 KB

    __shared__ __align__(16) __half Bs[16384];  // 32 KB (or 2 x 16 KB chunks)

    const int tid = threadIdx.x;
    const int wave = tid >> 6;
    const int lane = tid & 63;
    const int quad = lane >> 4;
    const int lmod = lane & 15;
    const int mbase = blockIdx.x * (64 * MT) + wave * 16 + lmod;

    int idx[MT][8];
    f16x8 invr[MT];
#pragma unroll
    for (int mt = 0; mt < MT; ++mt) {
        const int m = mbase + mt * 64;
        const int4* nrow = (const int4*)(nbr + (size_t)m * 8);
        const int4 iA = nrow[0];
        const int4 iB = nrow[1];
        idx[mt][0] = iA.x; idx[mt][1] = iA.y; idx[mt][2] = iA.z; idx[mt][3] = iA.w;
        idx[mt][4] = iB.x; idx[mt][5] = iB.y; idx[mt][6] = iB.z; idx[mt][7] = iB.w;
        invr[mt] = *(const f16x8*)(invd + (size_t)m * 8);
    }

    f32x4 acc[MT][NT];
#pragma unroll
    for (int mt = 0; mt < MT; ++mt)
#pragma unroll
        for (int t = 0; t < NT; ++t) acc[mt][t] = f32x4{0.f, 0.f, 0.f, 0.f};

    if constexpr (!CHUNKED) {
        // Stage the full 32 KB weight once; no barriers afterwards.
        {
            const uint4* src = (const uint4*)Wf;
            uint4* dst = (uint4*)Bs;
#pragma unroll
            for (int i = 0; i < 8; ++i) dst[i * 256 + tid] = src[i * 256 + tid];
        }
        __syncthreads();

        if constexpr (F_IN == 128) {
            // L2 layer: nb-loop with next-neighbor A prefetch.
            f16x8 a[2][MT][4];
#pragma unroll
            for (int mt = 0; mt < MT; ++mt)
#pragma unroll
                for (int ks = 0; ks < 4; ++ks)
                    a[0][mt][ks] = *(const f16x8*)(hprev + (size_t)idx[mt][0] * 128 + ks * 32 + quad * 8);
#pragma unroll
            for (int nb = 0; nb < 8; ++nb) {
                const int cur = nb & 1, nxt = cur ^ 1;
                if (nb < 7) {
#pragma unroll
                    for (int mt = 0; mt < MT; ++mt)
#pragma unroll
                        for (int ks = 0; ks < 4; ++ks)
                            a[nxt][mt][ks] = *(const f16x8*)(hprev + (size_t)idx[mt][nb + 1] * 128 + ks * 32 + quad * 8);
                }
#pragma unroll
                for (int ks = 0; ks < 4; ++ks) {
                    const int s = nb * 4 + ks;
                    f16x8 as[MT];
#pragma unroll
                    for (int mt = 0; mt < MT; ++mt) as[mt] = a[cur][mt][ks] * invr[mt][nb];
#pragma unroll
                    for (int t = 0; t < NT; ++t) {
                        f16x8 b = *(const f16x8*)(Bs + ((size_t)(s * NT + t) * 64 + lane) * 8);
#pragma unroll
                        for (int mt = 0; mt < MT; ++mt)
                            acc[mt][t] = __builtin_amdgcn_mfma_f32_16x16x32_f16(as[mt], b, acc[mt][t], 0, 0, 0);
                    }
                }
            }
        } else {
            // L0 layer (F_IN=16): K=128, nb = 2s + (quad>>1), feat = (quad&1)*8+j.
#pragma unroll
            for (int s = 0; s < 4; ++s) {
                const int nb = 2 * s + (quad >> 1);
                f16x8 as[MT];
#pragma unroll
                for (int mt = 0; mt < MT; ++mt) {
                    f16x8 av = *(const f16x8*)(hprev + (size_t)idx[mt][nb] * 16 + (quad & 1) * 8);
                    as[mt] = av * invr[mt][nb];
                }
#pragma unroll
                for (int t = 0; t < NT; ++t) {
                    f16x8 b = *(const f16x8*)(Bs + ((size_t)(s * NT + t) * 64 + lane) * 8);
#pragma unroll
                    for (int mt = 0; mt < MT; ++mt)
                        acc[mt][t] = __builtin_amdgcn_mfma_f32_16x16x32_f16(as[mt], b, acc[mt][t], 0, 0, 0);
                }
            }
        }
    } else {
        // L1: 16 half-neighbor stages, 16 KB weight chunks, double-buffered.
        f16x8 a[2][MT][4];
#pragma unroll
        for (int mt = 0; mt < MT; ++mt)
#pragma unroll
            for (int ks = 0; ks < 4; ++ks)
                a[0][mt][ks] = *(const f16x8*)(hprev + (size_t)idx[mt][0] * 128 + ks * 32 + quad * 8);
        {
            const uint4* src = (const uint4*)Wf;
            uint4* dst = (uint4*)Bs;
#pragma unroll
            for (int i = 0; i < 4; ++i) dst[i * 256 + tid] = src[i * 256 + tid];
        }
        __syncthreads();

#pragma unroll
        for (int st = 0; st < 16; ++st) {
            const int nb = st >> 1;
            const int half = st & 1;
            const int cur = nb & 1, nxt = cur ^ 1;

            // Issue next weight-chunk loads (consumed after the MFMAs below).
            uint4 btmp[4];
            if (st < 15) {
                const uint4* src = (const uint4*)(Wf + (size_t)(st + 1) * 8192);
#pragma unroll
                for (int i = 0; i < 4; ++i) btmp[i] = src[i * 256 + tid];
            }
            // Issue next-neighbor A gathers at even stages.
            if (half == 0 && nb < 7) {
#pragma unroll
                for (int mt = 0; mt < MT; ++mt)
#pragma unroll
                    for (int ks = 0; ks < 4; ++ks)
                        a[nxt][mt][ks] = *(const f16x8*)(hprev + (size_t)idx[mt][nb + 1] * 128 + ks * 32 + quad * 8);
            }

            // Compute this half-neighbor (2 k-steps) from LDS buffer st&1.
            const __half* bb = Bs + (size_t)(st & 1) * 8192;
#pragma unroll
            for (int kp = 0; kp < 2; ++kp) {
                const int ks = half * 2 + kp;
                f16x8 as[MT];
#pragma unroll
                for (int mt = 0; mt < MT; ++mt) as[mt] = a[cur][mt][ks] * invr[mt][nb];
#pragma unroll
                for (int t = 0; t < NT; ++t) {
                    f16x8 b = *(const f16x8*)(bb + ((size_t)(kp * NT + t) * 64 + lane) * 8);
#pragma unroll
                    for (int mt = 0; mt < MT; ++mt)
                        acc[mt][t] = __builtin_amdgcn_mfma_f32_16x16x32_f16(as[mt], b, acc[mt][t], 0, 0, 0);
                }
            }

            // Write next chunk into the other buffer, then sync.
            if (st < 15) {
                uint4* dst = (uint4*)(Bs + (size_t)((st + 1) & 1) * 8192);
#pragma unroll
                for (int i = 0; i < 4; ++i) dst[i * 256 + tid] = btmp[i];
            }
            __syncthreads();
        }
    }

    // Epilogue: D[row=quad*4+rr][col=lane&15] per 16x16 tile.
#pragma unroll
    for (int mt = 0; mt < MT; ++mt) {
        const int rbase = blockIdx.x * (64 * MT) + mt * 64 + wave * 16 + quad * 4;
#pragma unroll
        for (int t = 0; t < NT; ++t) {
            const int col = t * 16 + lmod;
            const float bv = bias[col];
#pragma unroll
            for (int rr = 0; rr < 4; ++rr) {
                const int grow = rbase + rr;
                float v = acc[mt][t][rr] * 256.0f + bv;
                if (LEAKY) v = (v >= 0.f) ? v : 0.01f * v;
                if (OUT_F32)
                    ((float*)outp)[(size_t)grow * F_OUT + col] = v;
                else
                    ((__half*)outp)[(size_t)grow * F_OUT + col] = __float2half(v);
            }
        }
    }
}

extern "C" void kernel_launch(void* const* d_in, const int* in_sizes, int n_in,
                              void* d_out, int out_size, void* d_ws, size_t ws_size,
                              hipStream_t stream) {
    const float* h   = (const float*)d_in[0];
    const float* pos = (const float*)d_in[1];
    const int*   nbr = (const int*)d_in[2];
    const float* W0  = (const float*)d_in[3];
    const float* b0  = (const float*)d_in[4];
    const float* W1  = (const float*)d_in[5];
    const float* b1  = (const float*)d_in[6];
    const float* W2  = (const float*)d_in[7];
    const float* b2  = (const float*)d_in[8];

    const int N = NNODES;

    // ws: ONLY the two 64 MiB fp16 intermediates (128 MiB total).
    char* w = (char*)d_ws;
    __half* h1 = (__half*)w;                               // 67,108,864 B
    __half* h2 = (__half*)(w + (size_t)67108864);          // 67,108,864 B
    // layer-2 copies of invd/Wf2, placed in the dead h1 region:
    __half* invd2 = (__half*)w;                            // 4,194,304 B
    __half* W2f2  = (__half*)(w + (size_t)4194304);        // 32,768 B

    // d_out doubles as scratch until layer 2 overwrites all of it (16 MiB).
    char* ob = (char*)d_out;
    __half* invd = (__half*)(ob + 0);                      // 4,194,304 B
    __half* h16  = (__half*)(ob + 4194304);                // 8,388,608 B
    __half* W0f  = (__half*)(ob + 12582912);               // 32,768 B
    __half* W1f  = (__half*)(ob + 12615680);               // 262,144 B
    __half* W2f  = (__half*)(ob + 12877824);               // 32,768 B  (end 12,910,592 <= 16,777,216)

    conv_h_kernel<<<(N * 16 + 255) / 256, 256, 0, stream>>>(h, h16, N * 16);
    prep_edges_kernel<<<(N * 8 + 255) / 256, 256, 0, stream>>>(pos, nbr, invd, N * 8);
    shuffle_w_kernel<<<(128 * 128 + 255) / 256, 256, 0, stream>>>(W0, W0f, 128, 128);
    shuffle_w_kernel<<<(1024 * 128 + 255) / 256, 256, 0, stream>>>(W1, W1f, 1024, 128);
    shuffle_w_kernel<<<(1024 * 16 + 255) / 256, 256, 0, stream>>>(W2, W2f, 1024, 16);

    layer_kernel<16, 128, 2, false, false><<<N / 128, 256, 0, stream>>>(h16, invd, nbr, W0f, b0, h1);
    layer_kernel<128, 128, 2, true, false><<<N / 128, 256, 0, stream>>>(h1, invd, nbr, W1f, b1, h2);

    // Move what layer 2 needs out of d_out (h1 is dead now).
    hipMemcpyAsync(invd2, invd, 4194304, hipMemcpyDeviceToDevice, stream);
    hipMemcpyAsync(W2f2, W2f, 32768, hipMemcpyDeviceToDevice, stream);

    layer_kernel<128, 16, 4, false, true><<<N / 256, 256, 0, stream>>>(h2, invd2, nbr, W2f2, b2, d_out);
}

// Round 6
// 373.689 us; speedup vs baseline: 1.1536x; 1.0981x over previous
//
#include <hip/hip_runtime.h>
#include <hip/hip_fp16.h>

// 3-layer gather-GEMM GNN (N=262144, K=8, 16->128->128->16), f16 MFMA.
// Round 6: full-A register prefetch (all 8 neighbors, 128 VGPR, MT=1) so the
// random-gather latency is paid ONCE per block instead of being re-drained at
// every stage barrier (the round-2..5 ~15%-MfmaUtil limiter). L1 weights
// double-buffered as full-neighbor 32 KB LDS chunks (one barrier/nb, only
// L2-resident weight loads outstanding at it); L2-layer weights staged once
// (barrier-free loop). L0 unchanged (stage-once, MT=2).
// Scaled messages prescaled by 2^-8 (folded into inv_dist); epilogue
// multiplies accumulator by 256 before bias.
//
// Workspace: ws holds ONLY h1+h2 (128 MiB exactly). invd/h16/shuffled-W live
// in d_out (scratch until layer 2 overwrites it); layer 2's invd+Wf2 are
// d2d-copied into the dead h1 region first.

typedef _Float16 f16x8 __attribute__((ext_vector_type(8)));
typedef float f32x4 __attribute__((ext_vector_type(4)));

#define NNODES 262144

__global__ __launch_bounds__(256) void conv_h_kernel(const float* __restrict__ h,
                                                     __half* __restrict__ h16, int n) {
    int i = blockIdx.x * 256 + threadIdx.x;
    if (i < n) h16[i] = __float2half(h[i]);
}

__global__ __launch_bounds__(256) void prep_edges_kernel(const float* __restrict__ pos,
                                                         const int* __restrict__ nbr,
                                                         __half* __restrict__ invd, int n_edges) {
    int e = blockIdx.x * 256 + threadIdx.x;
    if (e >= n_edges) return;
    int i = e >> 3;
    int n = nbr[e];
    float dx = pos[i * 3 + 0] - pos[n * 3 + 0];
    float dy = pos[i * 3 + 1] - pos[n * 3 + 1];
    float dz = pos[i * 3 + 2] - pos[n * 3 + 2];
    float d = sqrtf(dx * dx + dy * dy + dz * dz);
    if (d == 0.0f) d = 0.5f;                       // reference: where(dist==0, 0.5, dist)
    invd[e] = __float2half((1.0f / d) * 0.00390625f);  // prescale 1/256
}

// Pre-shuffle W [KT][FO] (row-major f32) into MFMA B-fragment order:
// Wf[((s*NT + t)*64 + lane)*8 + j] = W[s*32 + (lane>>4)*8 + j][t*16 + (lane&15)]
__global__ __launch_bounds__(256) void shuffle_w_kernel(const float* __restrict__ W,
                                                        __half* __restrict__ Wf,
                                                        int KT, int FO) {
    int e = blockIdx.x * 256 + threadIdx.x;
    if (e >= KT * FO) return;
    int j = e & 7;
    int lane = (e >> 3) & 63;
    int rest = e >> 9;
    int NT = FO >> 4;
    int t = rest % NT;
    int s = rest / NT;
    int k = s * 32 + (lane >> 4) * 8 + j;
    int n = t * 16 + (lane & 15);
    Wf[e] = __float2half(W[k * FO + n]);
}

// Fused gather + scale + GEMM layer.
template <int F_IN, int F_OUT, int MT, bool LEAKY, bool OUT_F32>
__global__ __launch_bounds__(256, 2) void layer_kernel(
    const __half* __restrict__ hprev, const __half* __restrict__ invd,
    const int* __restrict__ nbr, const __half* __restrict__ Wf,
    const float* __restrict__ bias, void* __restrict__ outp) {
    constexpr int NT = F_OUT / 16;
    constexpr bool CHUNKED = (F_IN == 128 && F_OUT == 128);  // Wf = 256 KB
    constexpr int BS_HALVES = CHUNKED ? 32768 : 16384;       // 64 KB : 32 KB

    __shared__ __align__(16) __half Bs[BS_HALVES];

    const int tid = threadIdx.x;
    const int wave = tid >> 6;
    const int lane = tid & 63;
    const int quad = lane >> 4;
    const int lmod = lane & 15;
    const int mbase = blockIdx.x * (64 * MT) + wave * 16 + lmod;

    int idx[MT][8];
    f16x8 invr[MT];
#pragma unroll
    for (int mt = 0; mt < MT; ++mt) {
        const int m = mbase + mt * 64;
        const int4* nrow = (const int4*)(nbr + (size_t)m * 8);
        const int4 iA = nrow[0];
        const int4 iB = nrow[1];
        idx[mt][0] = iA.x; idx[mt][1] = iA.y; idx[mt][2] = iA.z; idx[mt][3] = iA.w;
        idx[mt][4] = iB.x; idx[mt][5] = iB.y; idx[mt][6] = iB.z; idx[mt][7] = iB.w;
        invr[mt] = *(const f16x8*)(invd + (size_t)m * 8);
    }

    f32x4 acc[MT][NT];
#pragma unroll
    for (int mt = 0; mt < MT; ++mt)
#pragma unroll
        for (int t = 0; t < NT; ++t) acc[mt][t] = f32x4{0.f, 0.f, 0.f, 0.f};

    if constexpr (F_IN == 128) {
        // Full-A register prefetch: all 8 neighbors, issued before any barrier.
        // (MT must be 1 here: 8 nb x 4 ks x 4 VGPR = 128 VGPR.)
        f16x8 a[8][4];
#pragma unroll
        for (int nb = 0; nb < 8; ++nb) {
            const size_t base = (size_t)idx[0][nb] * 128;
#pragma unroll
            for (int ks = 0; ks < 4; ++ks)
                a[nb][ks] = *(const f16x8*)(hprev + base + ks * 32 + quad * 8);
        }

        if constexpr (CHUNKED) {
            // L1: stage weight chunk for nb=0 (32 KB), then one barrier per nb.
            {
                const uint4* src = (const uint4*)Wf;
                uint4* dst = (uint4*)Bs;
#pragma unroll
                for (int i = 0; i < 8; ++i) dst[i * 256 + tid] = src[i * 256 + tid];
            }
            __syncthreads();  // drains the full-A prefetch too (one-time cost)

#pragma unroll
            for (int nb = 0; nb < 8; ++nb) {
                // Prefetch next 32 KB weight chunk to registers (L2-resident).
                uint4 btmp[8];
                if (nb < 7) {
                    const uint4* src = (const uint4*)(Wf + (size_t)(nb + 1) * 16384);
#pragma unroll
                    for (int i = 0; i < 8; ++i) btmp[i] = src[i * 256 + tid];
                }

                const __half* bb = Bs + (nb & 1) * 16384;
#pragma unroll
                for (int ks = 0; ks < 4; ++ks) {
                    const f16x8 as = a[nb][ks] * invr[0][nb];
#pragma unroll
                    for (int t = 0; t < NT; ++t) {
                        f16x8 b = *(const f16x8*)(bb + ((size_t)(ks * NT + t) * 64 + lane) * 8);
                        acc[0][t] = __builtin_amdgcn_mfma_f32_16x16x32_f16(as, b, acc[0][t], 0, 0, 0);
                    }
                }

                if (nb < 7) {
                    uint4* dst = (uint4*)(Bs + ((nb + 1) & 1) * 16384);
#pragma unroll
                    for (int i = 0; i < 8; ++i) dst[i * 256 + tid] = btmp[i];
                    __syncthreads();  // only the weight chunk is outstanding here
                }
            }
        } else {
            // L2-layer: 32 KB weights staged once; barrier-free K-loop.
            {
                const uint4* src = (const uint4*)Wf;
                uint4* dst = (uint4*)Bs;
#pragma unroll
                for (int i = 0; i < 8; ++i) dst[i * 256 + tid] = src[i * 256 + tid];
            }
            __syncthreads();

#pragma unroll
            for (int nb = 0; nb < 8; ++nb) {
#pragma unroll
                for (int ks = 0; ks < 4; ++ks) {
                    const f16x8 as = a[nb][ks] * invr[0][nb];
                    const int s = nb * 4 + ks;
#pragma unroll
                    for (int t = 0; t < NT; ++t) {
                        f16x8 b = *(const f16x8*)(Bs + ((size_t)(s * NT + t) * 64 + lane) * 8);
                        acc[0][t] = __builtin_amdgcn_mfma_f32_16x16x32_f16(as, b, acc[0][t], 0, 0, 0);
                    }
                }
            }
        }
    } else {
        // L0 (F_IN=16): 32 KB weights staged once; K=128, nb = 2s + (quad>>1).
        {
            const uint4* src = (const uint4*)Wf;
            uint4* dst = (uint4*)Bs;
#pragma unroll
            for (int i = 0; i < 8; ++i) dst[i * 256 + tid] = src[i * 256 + tid];
        }
        __syncthreads();

#pragma unroll
        for (int s = 0; s < 4; ++s) {
            const int nb = 2 * s + (quad >> 1);
            f16x8 as[MT];
#pragma unroll
            for (int mt = 0; mt < MT; ++mt) {
                f16x8 av = *(const f16x8*)(hprev + (size_t)idx[mt][nb] * 16 + (quad & 1) * 8);
                as[mt] = av * invr[mt][nb];
            }
#pragma unroll
            for (int t = 0; t < NT; ++t) {
                f16x8 b = *(const f16x8*)(Bs + ((size_t)(s * NT + t) * 64 + lane) * 8);
#pragma unroll
                for (int mt = 0; mt < MT; ++mt)
                    acc[mt][t] = __builtin_amdgcn_mfma_f32_16x16x32_f16(as[mt], b, acc[mt][t], 0, 0, 0);
            }
        }
    }

    // Epilogue: D[row=quad*4+rr][col=lane&15] per 16x16 tile.
#pragma unroll
    for (int mt = 0; mt < MT; ++mt) {
        const int rbase = blockIdx.x * (64 * MT) + mt * 64 + wave * 16 + quad * 4;
#pragma unroll
        for (int t = 0; t < NT; ++t) {
            const int col = t * 16 + lmod;
            const float bv = bias[col];
#pragma unroll
            for (int rr = 0; rr < 4; ++rr) {
                const int grow = rbase + rr;
                float v = acc[mt][t][rr] * 256.0f + bv;
                if (LEAKY) v = (v >= 0.f) ? v : 0.01f * v;
                if (OUT_F32)
                    ((float*)outp)[(size_t)grow * F_OUT + col] = v;
                else
                    ((__half*)outp)[(size_t)grow * F_OUT + col] = __float2half(v);
            }
        }
    }
}

extern "C" void kernel_launch(void* const* d_in, const int* in_sizes, int n_in,
                              void* d_out, int out_size, void* d_ws, size_t ws_size,
                              hipStream_t stream) {
    const float* h   = (const float*)d_in[0];
    const float* pos = (const float*)d_in[1];
    const int*   nbr = (const int*)d_in[2];
    const float* W0  = (const float*)d_in[3];
    const float* b0  = (const float*)d_in[4];
    const float* W1  = (const float*)d_in[5];
    const float* b1  = (const float*)d_in[6];
    const float* W2  = (const float*)d_in[7];
    const float* b2  = (const float*)d_in[8];

    const int N = NNODES;

    // ws: ONLY the two 64 MiB fp16 intermediates (128 MiB total).
    char* w = (char*)d_ws;
    __half* h1 = (__half*)w;                               // 67,108,864 B
    __half* h2 = (__half*)(w + (size_t)67108864);          // 67,108,864 B
    // layer-2 copies of invd/Wf2, placed in the dead h1 region:
    __half* invd2 = (__half*)w;                            // 4,194,304 B
    __half* W2f2  = (__half*)(w + (size_t)4194304);        // 32,768 B

    // d_out doubles as scratch until layer 2 overwrites all of it (16 MiB).
    char* ob = (char*)d_out;
    __half* invd = (__half*)(ob + 0);                      // 4,194,304 B
    __half* h16  = (__half*)(ob + 4194304);                // 8,388,608 B
    __half* W0f  = (__half*)(ob + 12582912);               // 32,768 B
    __half* W1f  = (__half*)(ob + 12615680);               // 262,144 B
    __half* W2f  = (__half*)(ob + 12877824);               // 32,768 B  (end 12,910,592 <= 16,777,216)

    conv_h_kernel<<<(N * 16 + 255) / 256, 256, 0, stream>>>(h, h16, N * 16);
    prep_edges_kernel<<<(N * 8 + 255) / 256, 256, 0, stream>>>(pos, nbr, invd, N * 8);
    shuffle_w_kernel<<<(128 * 128 + 255) / 256, 256, 0, stream>>>(W0, W0f, 128, 128);
    shuffle_w_kernel<<<(1024 * 128 + 255) / 256, 256, 0, stream>>>(W1, W1f, 1024, 128);
    shuffle_w_kernel<<<(1024 * 16 + 255) / 256, 256, 0, stream>>>(W2, W2f, 1024, 16);

    layer_kernel<16, 128, 2, false, false><<<N / 128, 256, 0, stream>>>(h16, invd, nbr, W0f, b0, h1);
    layer_kernel<128, 128, 1, true, false><<<N / 64, 256, 0, stream>>>(h1, invd, nbr, W1f, b1, h2);

    // Move what layer 2 needs out of d_out (h1 is dead now).
    hipMemcpyAsync(invd2, invd, 4194304, hipMemcpyDeviceToDevice, stream);
    hipMemcpyAsync(W2f2, W2f, 32768, hipMemcpyDeviceToDevice, stream);

    layer_kernel<128, 16, 1, false, true><<<N / 64, 256, 0, stream>>>(h2, invd2, nbr, W2f2, b2, d_out);
}

// Round 8
// 333.324 us; speedup vs baseline: 1.2933x; 1.1211x over previous
//
#include <hip/hip_runtime.h>
#include <hip/hip_fp16.h>

// 3-layer gather-GEMM GNN (N=262144, K=8, 16->128->128->16), f16 MFMA.
// Round 7 (recompile of round-7 design; cast d_out to float*):
//  L1: t-specialized waves. Gathered A staged in LDS (2x 64x272B buffers,
//      padded -> conflict-free b128), B-fragments in registers prefetched one
//      neighbor ahead from L2 (no weight LDS). One barrier per nb; gathers and
//      nbr-index loads pipelined 1-2 nb ahead so the per-barrier vmcnt drain
//      only sees loads issued a full iteration earlier. 3 blocks/CU.
//  L2: rolling 3-deep A register prefetch, stage-once 32KB weights,
//      barrier-free K-loop, ~20 waves/CU for gather concurrency.
//  L0: stage-once weights, MT=2.
// Scaled messages prescaled by 2^-8 (folded into inv_dist); epilogue
// multiplies accumulator by 256 before bias.
//
// Workspace: ws holds ONLY h1+h2 (128 MiB exactly). invd/h16/shuffled-W live
// in d_out (scratch until layer 2 overwrites it); layer 2's invd+Wf2 are
// d2d-copied into the dead h1 region first.

typedef _Float16 f16x8 __attribute__((ext_vector_type(8)));
typedef float f32x4 __attribute__((ext_vector_type(4)));

#define NNODES 262144

__global__ __launch_bounds__(256) void conv_h_kernel(const float* __restrict__ h,
                                                     __half* __restrict__ h16, int n) {
    int i = blockIdx.x * 256 + threadIdx.x;
    if (i < n) h16[i] = __float2half(h[i]);
}

__global__ __launch_bounds__(256) void prep_edges_kernel(const float* __restrict__ pos,
                                                         const int* __restrict__ nbr,
                                                         __half* __restrict__ invd, int n_edges) {
    int e = blockIdx.x * 256 + threadIdx.x;
    if (e >= n_edges) return;
    int i = e >> 3;
    int n = nbr[e];
    float dx = pos[i * 3 + 0] - pos[n * 3 + 0];
    float dy = pos[i * 3 + 1] - pos[n * 3 + 1];
    float dz = pos[i * 3 + 2] - pos[n * 3 + 2];
    float d = sqrtf(dx * dx + dy * dy + dz * dz);
    if (d == 0.0f) d = 0.5f;                       // reference: where(dist==0, 0.5, dist)
    invd[e] = __float2half((1.0f / d) * 0.00390625f);  // prescale 1/256
}

// Pre-shuffle W [KT][FO] (row-major f32) into MFMA B-fragment order:
// Wf[((s*NT + t)*64 + lane)*8 + j] = W[s*32 + (lane>>4)*8 + j][t*16 + (lane&15)]
__global__ __launch_bounds__(256) void shuffle_w_kernel(const float* __restrict__ W,
                                                        __half* __restrict__ Wf,
                                                        int KT, int FO) {
    int e = blockIdx.x * 256 + threadIdx.x;
    if (e >= KT * FO) return;
    int j = e & 7;
    int lane = (e >> 3) & 63;
    int rest = e >> 9;
    int NT = FO >> 4;
    int t = rest % NT;
    int s = rest / NT;
    int k = s * 32 + (lane >> 4) * 8 + j;
    int n = t * 16 + (lane & 15);
    Wf[e] = __float2half(W[k * FO + n]);
}

// ---------------- L0: F_IN=16, F_OUT=128, 128 rows/block ----------------
__global__ __launch_bounds__(256) void layer0_kernel(
    const __half* __restrict__ hprev, const __half* __restrict__ invd,
    const int* __restrict__ nbr, const __half* __restrict__ Wf,
    const float* __restrict__ bias, __half* __restrict__ outp) {
    __shared__ __align__(16) __half Bs[16384];  // 32 KB weights, staged once

    const int tid = threadIdx.x;
    const int wave = tid >> 6;
    const int lane = tid & 63;
    const int quad = lane >> 4;
    const int lmod = lane & 15;
    const int mbase = blockIdx.x * 128 + wave * 16 + lmod;

    int idx[2][8];
    f16x8 invr[2];
#pragma unroll
    for (int mt = 0; mt < 2; ++mt) {
        const int m = mbase + mt * 64;
        const int4* nrow = (const int4*)(nbr + (size_t)m * 8);
        const int4 iA = nrow[0];
        const int4 iB = nrow[1];
        idx[mt][0] = iA.x; idx[mt][1] = iA.y; idx[mt][2] = iA.z; idx[mt][3] = iA.w;
        idx[mt][4] = iB.x; idx[mt][5] = iB.y; idx[mt][6] = iB.z; idx[mt][7] = iB.w;
        invr[mt] = *(const f16x8*)(invd + (size_t)m * 8);
    }

    f32x4 acc[2][8];
#pragma unroll
    for (int mt = 0; mt < 2; ++mt)
#pragma unroll
        for (int t = 0; t < 8; ++t) acc[mt][t] = f32x4{0.f, 0.f, 0.f, 0.f};

    {
        const uint4* src = (const uint4*)Wf;
        uint4* dst = (uint4*)Bs;
#pragma unroll
        for (int i = 0; i < 8; ++i) dst[i * 256 + tid] = src[i * 256 + tid];
    }
    __syncthreads();

#pragma unroll
    for (int s = 0; s < 4; ++s) {
        const int nb = 2 * s + (quad >> 1);
        f16x8 as[2];
#pragma unroll
        for (int mt = 0; mt < 2; ++mt) {
            f16x8 av = *(const f16x8*)(hprev + (size_t)idx[mt][nb] * 16 + (quad & 1) * 8);
            as[mt] = av * invr[mt][nb];
        }
#pragma unroll
        for (int t = 0; t < 8; ++t) {
            f16x8 b = *(const f16x8*)(Bs + ((size_t)(s * 8 + t) * 64 + lane) * 8);
#pragma unroll
            for (int mt = 0; mt < 2; ++mt)
                acc[mt][t] = __builtin_amdgcn_mfma_f32_16x16x32_f16(as[mt], b, acc[mt][t], 0, 0, 0);
        }
    }

#pragma unroll
    for (int mt = 0; mt < 2; ++mt) {
        const int rbase = blockIdx.x * 128 + mt * 64 + wave * 16 + quad * 4;
#pragma unroll
        for (int t = 0; t < 8; ++t) {
            const int col = t * 16 + lmod;
            const float bv = bias[col];
#pragma unroll
            for (int rr = 0; rr < 4; ++rr) {
                float v = acc[mt][t][rr] * 256.0f + bv;
                outp[(size_t)(rbase + rr) * 128 + col] = __float2half(v);
            }
        }
    }
}

// ---------------- L1: F_IN=128, F_OUT=128, 64 rows/block, t-specialized ----
__global__ __launch_bounds__(256, 3) void layer1_kernel(
    const __half* __restrict__ hprev, const __half* __restrict__ invd,
    const int* __restrict__ nbr, const __half* __restrict__ Wf,
    const float* __restrict__ bias, __half* __restrict__ outp) {
    __shared__ __align__(16) __half As[2][64][136];  // 272B rows: pad kills conflicts

    const int tid = threadIdx.x;
    const int wave = tid >> 6;
    const int lane = tid & 63;
    const int quad = lane >> 4;
    const int lmod = lane & 15;
    const int rowblk = blockIdx.x * 64;
    const int seg = lmod;  // 16B segment within a 256B row (staging)

    // Staging rows for this wave: 4 insts x 4 rows (quad picks row-in-inst).
    int srow[4], grow_[4];
#pragma unroll
    for (int i = 0; i < 4; ++i) { srow[i] = wave * 16 + i * 4 + quad; grow_[i] = rowblk + srow[i]; }

    f16x8 invS[4];
#pragma unroll
    for (int i = 0; i < 4; ++i) invS[i] = *(const f16x8*)(invd + (size_t)grow_[i] * 8);

    // Index pipeline: idxP[(nb+1)&1] holds idx for nb+1 at start of iter nb.
    int idx0[4], idxP[2][4];
#pragma unroll
    for (int i = 0; i < 4; ++i) idx0[i] = nbr[(size_t)grow_[i] * 8 + 0];
#pragma unroll
    for (int i = 0; i < 4; ++i) idxP[1][i] = nbr[(size_t)grow_[i] * 8 + 1];

    // This wave's two output col-tiles: t = wave*2 + tl.
    const __half* WfB = Wf + ((size_t)(wave * 2) * 64 + lane) * 8;

    f16x8 Bc[4][2], Bn[4][2];
#pragma unroll
    for (int ks = 0; ks < 4; ++ks)
#pragma unroll
        for (int tl = 0; tl < 2; ++tl)
            Bc[ks][tl] = *(const f16x8*)(WfB + (size_t)(ks * 8 + tl) * 512);

    // Stage nb=0.
    f16x8 ga[4];
#pragma unroll
    for (int i = 0; i < 4; ++i)
        ga[i] = *(const f16x8*)(hprev + (size_t)idx0[i] * 128 + seg * 8);
#pragma unroll
    for (int i = 0; i < 4; ++i) {
        f16x8 v = ga[i] * invS[i][0];
        *(f16x8*)(&As[0][srow[i]][seg * 8]) = v;
    }
    __syncthreads();

    f32x4 acc[4][2];
#pragma unroll
    for (int m = 0; m < 4; ++m) { acc[m][0] = f32x4{0.f,0.f,0.f,0.f}; acc[m][1] = f32x4{0.f,0.f,0.f,0.f}; }

#pragma unroll
    for (int nb = 0; nb < 8; ++nb) {
        const int cur = nb & 1;
        // Issue gathers for nb+1 (indices arrived a full iteration ago).
        if (nb < 7) {
#pragma unroll
            for (int i = 0; i < 4; ++i)
                ga[i] = *(const f16x8*)(hprev + (size_t)idxP[(nb + 1) & 1][i] * 128 + seg * 8);
        }
        // Issue index loads for nb+2 into the slot freed by nb.
        if (nb < 6) {
#pragma unroll
            for (int i = 0; i < 4; ++i)
                idxP[nb & 1][i] = nbr[(size_t)grow_[i] * 8 + nb + 2];
        }
        // Issue B-fragment loads for nb+1 (L2-resident stream).
        if (nb < 7) {
#pragma unroll
            for (int ks = 0; ks < 4; ++ks)
#pragma unroll
                for (int tl = 0; tl < 2; ++tl)
                    Bn[ks][tl] = *(const f16x8*)(WfB + (size_t)(((nb + 1) * 4 + ks) * 8 + tl) * 512);
        }
        // Compute nb: 16 ds_read_b128, 32 MFMA (each A frag feeds 2 MFMAs).
#pragma unroll
        for (int m = 0; m < 4; ++m) {
#pragma unroll
            for (int ks = 0; ks < 4; ++ks) {
                f16x8 a = *(const f16x8*)(&As[cur][m * 16 + lmod][ks * 32 + quad * 8]);
                acc[m][0] = __builtin_amdgcn_mfma_f32_16x16x32_f16(a, Bc[ks][0], acc[m][0], 0, 0, 0);
                acc[m][1] = __builtin_amdgcn_mfma_f32_16x16x32_f16(a, Bc[ks][1], acc[m][1], 0, 0, 0);
            }
        }
        // Stage nb+1 into the other buffer; rotate B; one barrier per nb.
        if (nb < 7) {
#pragma unroll
            for (int i = 0; i < 4; ++i) {
                f16x8 v = ga[i] * invS[i][nb + 1];
                *(f16x8*)(&As[cur ^ 1][srow[i]][seg * 8]) = v;
            }
#pragma unroll
            for (int ks = 0; ks < 4; ++ks) { Bc[ks][0] = Bn[ks][0]; Bc[ks][1] = Bn[ks][1]; }
            __syncthreads();
        }
    }

    // Epilogue: rows 0..63, cols wave*32..+32. LeakyReLU.
#pragma unroll
    for (int m = 0; m < 4; ++m) {
#pragma unroll
        for (int tl = 0; tl < 2; ++tl) {
            const int col = wave * 32 + tl * 16 + lmod;
            const float bv = bias[col];
#pragma unroll
            for (int rr = 0; rr < 4; ++rr) {
                const int grow = rowblk + m * 16 + quad * 4 + rr;
                float v = acc[m][tl][rr] * 256.0f + bv;
                v = (v >= 0.f) ? v : 0.01f * v;
                outp[(size_t)grow * 128 + col] = __float2half(v);
            }
        }
    }
}

// ---------------- L2: F_IN=128, F_OUT=16, 64 rows/block, rolling gather ----
__global__ __launch_bounds__(256) void layer2_kernel(
    const __half* __restrict__ hprev, const __half* __restrict__ invd,
    const int* __restrict__ nbr, const __half* __restrict__ Wf,
    const float* __restrict__ bias, float* __restrict__ outp) {
    __shared__ __align__(16) __half Bs[16384];  // 32 KB weights, staged once

    const int tid = threadIdx.x;
    const int wave = tid >> 6;
    const int lane = tid & 63;
    const int quad = lane >> 4;
    const int lmod = lane & 15;
    const int m = blockIdx.x * 64 + wave * 16 + lmod;

    const int4* nrow = (const int4*)(nbr + (size_t)m * 8);
    const int4 iA = nrow[0];
    const int4 iB = nrow[1];
    const int idx[8] = {iA.x, iA.y, iA.z, iA.w, iB.x, iB.y, iB.z, iB.w};
    const f16x8 invr = *(const f16x8*)(invd + (size_t)m * 8);

    {
        const uint4* src = (const uint4*)Wf;
        uint4* dst = (uint4*)Bs;
#pragma unroll
        for (int i = 0; i < 8; ++i) dst[i * 256 + tid] = src[i * 256 + tid];
    }
    __syncthreads();

    // Rolling 3-deep neighbor prefetch; barrier-free loop.
    f16x8 a[3][4];
#pragma unroll
    for (int d = 0; d < 3; ++d)
#pragma unroll
        for (int ks = 0; ks < 4; ++ks)
            a[d][ks] = *(const f16x8*)(hprev + (size_t)idx[d] * 128 + ks * 32 + quad * 8);

    f32x4 acc = f32x4{0.f, 0.f, 0.f, 0.f};
#pragma unroll
    for (int nb = 0; nb < 8; ++nb) {
        const int slot = nb % 3;
#pragma unroll
        for (int ks = 0; ks < 4; ++ks) {
            f16x8 as = a[slot][ks] * invr[nb];
            f16x8 b = *(const f16x8*)(Bs + ((size_t)(nb * 4 + ks) * 64 + lane) * 8);
            acc = __builtin_amdgcn_mfma_f32_16x16x32_f16(as, b, acc, 0, 0, 0);
        }
        if (nb < 5) {
#pragma unroll
            for (int ks = 0; ks < 4; ++ks)
                a[slot][ks] = *(const f16x8*)(hprev + (size_t)idx[nb + 3] * 128 + ks * 32 + quad * 8);
        }
    }

    const int rbase = blockIdx.x * 64 + wave * 16 + quad * 4;
    const float bv = bias[lmod];
#pragma unroll
    for (int rr = 0; rr < 4; ++rr)
        outp[(size_t)(rbase + rr) * 16 + lmod] = acc[rr] * 256.0f + bv;
}

extern "C" void kernel_launch(void* const* d_in, const int* in_sizes, int n_in,
                              void* d_out, int out_size, void* d_ws, size_t ws_size,
                              hipStream_t stream) {
    const float* h   = (const float*)d_in[0];
    const float* pos = (const float*)d_in[1];
    const int*   nbr = (const int*)d_in[2];
    const float* W0  = (const float*)d_in[3];
    const float* b0  = (const float*)d_in[4];
    const float* W1  = (const float*)d_in[5];
    const float* b1  = (const float*)d_in[6];
    const float* W2  = (const float*)d_in[7];
    const float* b2  = (const float*)d_in[8];

    const int N = NNODES;

    // ws: ONLY the two 64 MiB fp16 intermediates (128 MiB total).
    char* w = (char*)d_ws;
    __half* h1 = (__half*)w;                               // 67,108,864 B
    __half* h2 = (__half*)(w + (size_t)67108864);          // 67,108,864 B
    // layer-2 copies of invd/Wf2, placed in the dead h1 region:
    __half* invd2 = (__half*)w;                            // 4,194,304 B
    __half* W2f2  = (__half*)(w + (size_t)4194304);        // 32,768 B

    // d_out doubles as scratch until layer 2 overwrites all of it (16 MiB).
    char* ob = (char*)d_out;
    __half* invd = (__half*)(ob + 0);                      // 4,194,304 B
    __half* h16  = (__half*)(ob + 4194304);                // 8,388,608 B
    __half* W0f  = (__half*)(ob + 12582912);               // 32,768 B
    __half* W1f  = (__half*)(ob + 12615680);               // 262,144 B
    __half* W2f  = (__half*)(ob + 12877824);               // 32,768 B  (end 12,910,592 <= 16,777,216)

    conv_h_kernel<<<(N * 16 + 255) / 256, 256, 0, stream>>>(h, h16, N * 16);
    prep_edges_kernel<<<(N * 8 + 255) / 256, 256, 0, stream>>>(pos, nbr, invd, N * 8);
    shuffle_w_kernel<<<(128 * 128 + 255) / 256, 256, 0, stream>>>(W0, W0f, 128, 128);
    shuffle_w_kernel<<<(1024 * 128 + 255) / 256, 256, 0, stream>>>(W1, W1f, 1024, 128);
    shuffle_w_kernel<<<(1024 * 16 + 255) / 256, 256, 0, stream>>>(W2, W2f, 1024, 16);

    layer0_kernel<<<N / 128, 256, 0, stream>>>(h16, invd, nbr, W0f, b0, h1);
    layer1_kernel<<<N / 64, 256, 0, stream>>>(h1, invd, nbr, W1f, b1, h2);

    // Move what layer 2 needs out of d_out (h1 is dead now).
    (void)hipMemcpyAsync(invd2, invd, 4194304, hipMemcpyDeviceToDevice, stream);
    (void)hipMemcpyAsync(W2f2, W2f, 32768, hipMemcpyDeviceToDevice, stream);

    layer2_kernel<<<N / 64, 256, 0, stream>>>(h2, invd2, nbr, W2f2, b2, (float*)d_out);
}